// Round 10
// baseline (486.549 us; speedup 1.0000x reference)
//
#include <hip/hip_runtime.h>
#include <math.h>

#define NFOUR 512
#define NSEG 16
#define SEG 64
#define SLEN 1024
#define BB 32
#define CH 16
#define MU_F 10.0f
// -MU*T*(2*pi)^(D-1) = -100 * (2*pi)^2
#define LL2_F (-3947.8417604357435f)
#define MAGIC 0x1357246   // != 0xAAAAAAAA ws-poison

__global__ __launch_bounds__(256) void k_mlp(
    const float* __restrict__ noise, const float* __restrict__ W1,
    const float* __restrict__ b1, const float* __restrict__ W2,
    const float* __restrict__ b2, const float* __restrict__ Wm,
    float* __restrict__ wsw)
{
    int n = blockIdx.x;
    int t = threadIdx.x;
    __shared__ float nz[64];
    __shared__ float h1[100];
    __shared__ float red[3][4];
    if (t < 64) nz[t] = noise[n * 64 + t];
    __syncthreads();
    if (t < 100) {
        float acc = b1[t];
        #pragma unroll
        for (int k = 0; k < 64; ++k) acc += nz[k] * W1[k * 100 + t];
        h1[t] = tanhf(acc);
    }
    __syncthreads();
    float acc = b2[t];
    #pragma unroll 4
    for (int k = 0; k < 100; ++k) acc += h1[k] * W2[k * 256 + t];
    float h2 = tanhf(acc);
    float pd0 = h2 * Wm[t * 3 + 0];
    float pd1 = h2 * Wm[t * 3 + 1];
    float pd2 = h2 * Wm[t * 3 + 2];
    #pragma unroll
    for (int off = 32; off; off >>= 1) {
        pd0 += __shfl_xor(pd0, off);
        pd1 += __shfl_xor(pd1, off);
        pd2 += __shfl_xor(pd2, off);
    }
    if ((t & 63) == 0) {
        red[0][t >> 6] = pd0;
        red[1][t >> 6] = pd1;
        red[2][t >> 6] = pd2;
    }
    __syncthreads();
    if (t == 0) {
        wsw[n]             = red[0][0] + red[0][1] + red[0][2] + red[0][3];
        wsw[NFOUR + n]     = red[1][0] + red[1][1] + red[1][2] + red[1][3];
        wsw[2 * NFOUR + n] = red[2][0] + red[2][1] + red[2][2] + red[2][3];
    }
}

// fused seg-sums + decoupled-lookback + main pass
__global__ __launch_bounds__(512, 4) void k_scan(
    const float* __restrict__ X, const float* __restrict__ wsw,
    const float* __restrict__ alpha, float* __restrict__ segC,
    float* __restrict__ segS, int* __restrict__ sflag,
    float* __restrict__ out)
{
    int bid = blockIdx.x;
    int b = bid >> 4, g = bid & 15;
    int t = threadIdx.x;
    __shared__ float4 xs4[SEG];
    __shared__ float buf[CH][NFOUR];
    if (t < SEG * 3) {
        ((float*)&xs4[t / 3])[t % 3] = X[(b * SLEN + g * SEG) * 3 + t];
    }
    __syncthreads();
    float w0 = wsw[t], w1 = wsw[NFOUR + t], w2 = wsw[2 * NFOUR + t];
    float a0 = alpha[0];

    // ---- phase 1: this block's segment sums, publish with release flag ----
    float cA = 0.f, sA = 0.f;
    #pragma unroll 8
    for (int i = 0; i < SEG; ++i) {
        float4 x = xs4[i];
        float th = x.x * w0 + x.y * w1 + x.z * w2;
        float sn, cs;
        __sincosf(th, &sn, &cs);
        cA += cs;
        sA += sn;
    }
    segC[bid * NFOUR + t] = cA;
    segS[bid * NFOUR + t] = sA;
    __syncthreads();          // all lanes' stores issued
    __threadfence();          // agent-scope visibility for the row
    if (t == 0) {
        __hip_atomic_store(&sflag[bid], MAGIC, __ATOMIC_RELEASE,
                           __HIP_MEMORY_SCOPE_AGENT);
    }

    // ---- lookback: exclusive prefix over predecessor segments ----
    float cC = 0.f, sS = 0.f;
    for (int gp = 0; gp < g; ++gp) {
        int fi = (b << 4) | gp;
        while (__hip_atomic_load(&sflag[fi], __ATOMIC_ACQUIRE,
                                 __HIP_MEMORY_SCOPE_AGENT) != MAGIC) {
            __builtin_amdgcn_s_sleep(1);
        }
        cC += segC[fi * NFOUR + t];
        sS += segS[fi * NFOUR + t];
    }

    // ---- phase 2: per-s contributions, transpose-reduce, outputs ----
    int r = t >> 5, c = t & 31;
    for (int ch = 0; ch < 4; ++ch) {
        #pragma unroll
        for (int i = 0; i < CH; ++i) {
            int s = ch * CH + i;
            float4 x = xs4[s];
            float th = x.x * w0 + x.y * w1 + x.z * w2;
            float sn, cs;
            __sincosf(th, &sn, &cs);
            buf[i][t] = cs * cC + sn * sS;   // exclusive prefix contribution
            cC += cs;
            sS += sn;
        }
        __syncthreads();
        float4 v0 = *(const float4*)&buf[r][c * 4 + 0];
        float4 v1 = *(const float4*)&buf[r][c * 4 + 128];
        float4 v2 = *(const float4*)&buf[r][c * 4 + 256];
        float4 v3 = *(const float4*)&buf[r][c * 4 + 384];
        float acc = (v0.x + v0.y + v0.z + v0.w) + (v1.x + v1.y + v1.z + v1.w)
                  + (v2.x + v2.y + v2.z + v2.w) + (v3.x + v3.y + v3.z + v3.w);
        acc += __shfl_xor(acc, 16);
        acc += __shfl_xor(acc, 8);
        acc += __shfl_xor(acc, 4);
        acc += __shfl_xor(acc, 2);
        acc += __shfl_xor(acc, 1);
        if (c == 0) {
            int s = ch * CH + r;
            float lam = a0 * acc * (1.0f / (float)NFOUR) + MU_F;
            int sg = g * SEG + s;
            out[b * SLEN + sg] = lam;
            float m = (xs4[s].x > 0.f) ? 1.f : 0.f;
            out[BB * SLEN + b * (SLEN + 1) + sg] = __logf(lam) * m + LL2_F;
        }
        __syncthreads();
    }
    // tail column loglik[:, S] = LL2 (32 values), done once by blocks g==0
    if (g == 0 && t >= 64 && t < 64 + BB) {
        out[BB * SLEN + (t - 64) * (SLEN + 1) + SLEN] = LL2_F;
    }
}

extern "C" void kernel_launch(void* const* d_in, const int* in_sizes, int n_in,
                              void* d_out, int out_size, void* d_ws, size_t ws_size,
                              hipStream_t stream) {
    const float* X     = (const float*)d_in[0];
    const float* noise = (const float*)d_in[1];
    const float* W1    = (const float*)d_in[2];
    const float* b1    = (const float*)d_in[3];
    const float* W2    = (const float*)d_in[4];
    const float* b2    = (const float*)d_in[5];
    const float* Wm    = (const float*)d_in[6];
    const float* alpha = (const float*)d_in[7];
    float* out = (float*)d_out;
    float* ws  = (float*)d_ws;

    float* wsw  = ws;                        // 3*512 floats (Womg, SoA)
    float* segC = ws + 2048;                 // 512*512 floats
    float* segS = segC + BB * NSEG * NFOUR;  // 512*512 floats
    int*   sflg = (int*)(segS + BB * NSEG * NFOUR);  // 512 flags (poison != MAGIC)

    k_mlp<<<NFOUR, 256, 0, stream>>>(noise, W1, b1, W2, b2, Wm, wsw);
    k_scan<<<BB * NSEG, 512, 0, stream>>>(X, wsw, alpha, segC, segS, sflg, out);
}

// Round 11
// 98.324 us; speedup vs baseline: 4.9484x; 4.9484x over previous
//
#include <hip/hip_runtime.h>
#include <math.h>

#define NFOUR 512
#define NSEG 16
#define SEG 64
#define SLEN 1024
#define BB 32
#define CH 16
#define MU_F 10.0f
// -MU*T*(2*pi)^(D-1) = -100 * (2*pi)^2
#define LL2_F (-3947.8417604357435f)

__global__ __launch_bounds__(256) void k_mlp(
    const float* __restrict__ noise, const float* __restrict__ W1,
    const float* __restrict__ b1, const float* __restrict__ W2,
    const float* __restrict__ b2, const float* __restrict__ Wm,
    float* __restrict__ wsw)
{
    int n = blockIdx.x;
    int t = threadIdx.x;
    __shared__ float nz[64];
    __shared__ float h1[100];
    __shared__ float red[3][4];
    if (t < 64) nz[t] = noise[n * 64 + t];
    __syncthreads();
    if (t < 100) {
        float acc = b1[t];
        #pragma unroll
        for (int k = 0; k < 64; ++k) acc += nz[k] * W1[k * 100 + t];
        h1[t] = tanhf(acc);
    }
    __syncthreads();
    float acc = b2[t];
    #pragma unroll 4
    for (int k = 0; k < 100; ++k) acc += h1[k] * W2[k * 256 + t];
    float h2 = tanhf(acc);
    float pd0 = h2 * Wm[t * 3 + 0];
    float pd1 = h2 * Wm[t * 3 + 1];
    float pd2 = h2 * Wm[t * 3 + 2];
    #pragma unroll
    for (int off = 32; off; off >>= 1) {
        pd0 += __shfl_xor(pd0, off);
        pd1 += __shfl_xor(pd1, off);
        pd2 += __shfl_xor(pd2, off);
    }
    if ((t & 63) == 0) {
        red[0][t >> 6] = pd0;
        red[1][t >> 6] = pd1;
        red[2][t >> 6] = pd2;
    }
    __syncthreads();
    if (t == 0) {
        wsw[n]             = red[0][0] + red[0][1] + red[0][2] + red[0][3];
        wsw[NFOUR + n]     = red[1][0] + red[1][1] + red[1][2] + red[1][3];
        wsw[2 * NFOUR + n] = red[2][0] + red[2][1] + red[2][2] + red[2][3];
    }
}

__global__ __launch_bounds__(512) void k_seg(
    const float* __restrict__ X, const float* __restrict__ wsw,
    float* __restrict__ segC, float* __restrict__ segS)
{
    int b = blockIdx.x / NSEG, g = blockIdx.x % NSEG;
    int n = threadIdx.x;
    __shared__ float4 xs4[SEG];
    if (n < SEG * 3) {
        // scatter 3-float rows into padded float4 slots
        ((float*)&xs4[n / 3])[n % 3] = X[(b * SLEN + g * SEG) * 3 + n];
    }
    __syncthreads();
    float w0 = wsw[n], w1 = wsw[NFOUR + n], w2 = wsw[2 * NFOUR + n];
    float cA = 0.f, sA = 0.f;
    #pragma unroll 8
    for (int i = 0; i < SEG; ++i) {
        float4 x = xs4[i];                 // one ds_read_b128, broadcast
        float th = x.x * w0 + x.y * w1 + x.z * w2;
        float sn, cs;
        __sincosf(th, &sn, &cs);
        cA += cs;
        sA += sn;
    }
    segC[(b * NSEG + g) * NFOUR + n] = cA;
    segS[(b * NSEG + g) * NFOUR + n] = sA;
}

__global__ __launch_bounds__(512) void k_main(
    const float* __restrict__ X, const float* __restrict__ wsw,
    const float* __restrict__ segC, const float* __restrict__ segS,
    const float* __restrict__ alpha, float* __restrict__ out)
{
    int b = blockIdx.x / NSEG, g = blockIdx.x % NSEG;
    int n = threadIdx.x;
    __shared__ float4 xs4[SEG];
    __shared__ float buf[CH][NFOUR];
    if (n < SEG * 3) {
        ((float*)&xs4[n / 3])[n % 3] = X[(b * SLEN + g * SEG) * 3 + n];
    }
    float cC = 0.f, sS = 0.f;
    for (int gp = 0; gp < g; ++gp) {
        cC += segC[(b * NSEG + gp) * NFOUR + n];
        sS += segS[(b * NSEG + gp) * NFOUR + n];
    }
    float w0 = wsw[n], w1 = wsw[NFOUR + n], w2 = wsw[2 * NFOUR + n];
    float a0 = alpha[0];
    __syncthreads();
    int r = n >> 5, c = n & 31;
    for (int ch = 0; ch < 4; ++ch) {
        #pragma unroll
        for (int i = 0; i < CH; ++i) {
            int s = ch * CH + i;
            float4 x = xs4[s];             // one ds_read_b128, broadcast
            float th = x.x * w0 + x.y * w1 + x.z * w2;
            float sn, cs;
            __sincosf(th, &sn, &cs);
            buf[i][n] = cs * cC + sn * sS; // exclusive prefix contribution
            cC += cs;
            sS += sn;
        }
        __syncthreads();
        // transpose-reduce: 32 threads per row, each sums 16 floats (4x b128)
        float4 v0 = *(const float4*)&buf[r][c * 4 + 0];
        float4 v1 = *(const float4*)&buf[r][c * 4 + 128];
        float4 v2 = *(const float4*)&buf[r][c * 4 + 256];
        float4 v3 = *(const float4*)&buf[r][c * 4 + 384];
        float acc = (v0.x + v0.y + v0.z + v0.w) + (v1.x + v1.y + v1.z + v1.w)
                  + (v2.x + v2.y + v2.z + v2.w) + (v3.x + v3.y + v3.z + v3.w);
        acc += __shfl_xor(acc, 16);
        acc += __shfl_xor(acc, 8);
        acc += __shfl_xor(acc, 4);
        acc += __shfl_xor(acc, 2);
        acc += __shfl_xor(acc, 1);
        if (c == 0) {
            int s = ch * CH + r;
            float lam = a0 * acc * (1.0f / (float)NFOUR) + MU_F;
            int sg = g * SEG + s;
            out[b * SLEN + sg] = lam;
            float m = (xs4[s].x > 0.f) ? 1.f : 0.f;
            out[BB * SLEN + b * (SLEN + 1) + sg] = __logf(lam) * m + LL2_F;
        }
        __syncthreads();
    }
    // tail column loglik[:, S] = LL2 (32 values), done once by block g==0
    if (g == 0 && n >= 64 && n < 64 + BB) {
        out[BB * SLEN + (n - 64) * (SLEN + 1) + SLEN] = LL2_F;
    }
}

extern "C" void kernel_launch(void* const* d_in, const int* in_sizes, int n_in,
                              void* d_out, int out_size, void* d_ws, size_t ws_size,
                              hipStream_t stream) {
    const float* X     = (const float*)d_in[0];
    const float* noise = (const float*)d_in[1];
    const float* W1    = (const float*)d_in[2];
    const float* b1    = (const float*)d_in[3];
    const float* W2    = (const float*)d_in[4];
    const float* b2    = (const float*)d_in[5];
    const float* Wm    = (const float*)d_in[6];
    const float* alpha = (const float*)d_in[7];
    float* out = (float*)d_out;
    float* ws  = (float*)d_ws;

    float* wsw  = ws;                       // 3*512 floats (Womg, SoA)
    float* segC = ws + 2048;                // B*NSEG*NF floats
    float* segS = segC + BB * NSEG * NFOUR; // B*NSEG*NF floats

    k_mlp<<<NFOUR, 256, 0, stream>>>(noise, W1, b1, W2, b2, Wm, wsw);
    k_seg<<<BB * NSEG, 512, 0, stream>>>(X, wsw, segC, segS);
    k_main<<<BB * NSEG, 512, 0, stream>>>(X, wsw, segC, segS, alpha, out);
}